// Round 4
// baseline (235.911 us; speedup 1.0000x reference)
//
#include <hip/hip_runtime.h>
#include <math.h>

// MoE top-2-of-8: B=1024, I=512, H=2048, O=512, E=8, K=2.
// R12: latency fix, round 2. R11 counters showed fc1's waves fully serialize
// their global loads (~1000 cyc/load, VGPR=48 -> compiler built no pipeline;
// occupancy 13.7% = grid-limited 8 waves/CU). Changes:
//  1) depth-4 rotating register prefetch in fc1/fc2 inner loops (fully
//     unrolled, static indices) -> 16 loads in flight per wave.
//  2) fc1: BN 64->32 (JN=2), grid (64,2,8)=1024 blocks -> 16 waves/CU.
//     __launch_bounds__(256,4) caps VGPR at 128 (pipeline ~100 VGPR).
//  3) fc2: same prefetch, grid (16,4,8)=512 blocks (kc=2 -> y2 partials).
// Pipeline: prep (gating + W1/W2 -> bf16 [n][k] transpose), fc1, fc2,
// combine. NOTE: dur_us includes ~81us of harness 256MB poison fills
// (2 x 40.5us) -- the controllable kernel budget is dur_us minus that.

#define B_TOK 1024
#define I_DIM 512
#define H_DIM 2048
#define O_DIM 512
#define E_NUM 8
#define CAP   1024                       // per-expert slot capacity

#define WS_COUNTS   0                    // 8 ints (written by fc1 nx==0,my==0)
#define WS_TOK_E    64                   // [1024][2] int
#define WS_TOK_W    8256                 // [1024][2] float
#define WS_TOK_SLOT 16448                // [1024][2] int
#define WS_XB       65536                // [1024][512] bf16 = 1 MB
#define WS_W1T      1114112              // [8][2048][512] bf16 = 16 MB
#define WS_W2T      17891328             // [8][512][2048] bf16 = 16 MB
#define WS_HB       34668544             // [8*1024][2048] bf16 = 32 MB
#define WS_Y2       68222976             // [2][8192][512] f32 = 32 MB

typedef __attribute__((ext_vector_type(8))) __bf16 bf16x8;
typedef __attribute__((ext_vector_type(4))) __bf16 bf16x4;
typedef __attribute__((ext_vector_type(2))) __bf16 bf16x2;
typedef __attribute__((ext_vector_type(4))) float f32x4;

#define MFMA16 __builtin_amdgcn_mfma_f32_16x16x32_bf16

// ---------------------------------------------------------------------------
// prep: blocks 0..255 gate 4 tokens each (one per wave) + convert x->xb bf16;
// ALL 1024 blocks then transpose one 64k x 256n W-tile to bf16 [n][k].
__global__ __launch_bounds__(256) void prep_kernel(
    const float* __restrict__ x, const float* __restrict__ Wg,
    const float* __restrict__ bg, const float* __restrict__ W1f,
    const float* __restrict__ W2f,
    __bf16* __restrict__ xb, int* __restrict__ tok_e,
    float* __restrict__ tok_w,
    __bf16* __restrict__ W1T, __bf16* __restrict__ W2T)
{
    const int tid = threadIdx.x, lane = tid & 63, w = tid >> 6;
    const int b = blockIdx.x;

    // ---- gating (blocks 0..255, one token per wave) ----
    if (b < 256) {
        const int t = b * 4 + w;
        const float4* x4 = (const float4*)(x + (size_t)t * I_DIM);
        float4 va = x4[lane], vb = x4[lane + 64];
        bf16x4 oa, ob;
        oa[0] = (__bf16)va.x; oa[1] = (__bf16)va.y;
        oa[2] = (__bf16)va.z; oa[3] = (__bf16)va.w;
        ob[0] = (__bf16)vb.x; ob[1] = (__bf16)vb.y;
        ob[2] = (__bf16)vb.z; ob[3] = (__bf16)vb.w;
        *(bf16x4*)(xb + (size_t)t * I_DIM + lane * 4) = oa;
        *(bf16x4*)(xb + (size_t)t * I_DIM + 256 + lane * 4) = ob;

        float gacc[8];
#pragma unroll
        for (int e = 0; e < 8; ++e) gacc[e] = 0.f;
        float xv[8] = {va.x, va.y, va.z, va.w, vb.x, vb.y, vb.z, vb.w};
#pragma unroll
        for (int u = 0; u < 8; ++u) {
            int i = (u < 4) ? (lane * 4 + u) : (256 + lane * 4 + u - 4);
            const float4* wr = (const float4*)(Wg + (size_t)i * 8);
            float4 wa = wr[0], wb2 = wr[1];
            gacc[0] = fmaf(xv[u], wa.x, gacc[0]);
            gacc[1] = fmaf(xv[u], wa.y, gacc[1]);
            gacc[2] = fmaf(xv[u], wa.z, gacc[2]);
            gacc[3] = fmaf(xv[u], wa.w, gacc[3]);
            gacc[4] = fmaf(xv[u], wb2.x, gacc[4]);
            gacc[5] = fmaf(xv[u], wb2.y, gacc[5]);
            gacc[6] = fmaf(xv[u], wb2.z, gacc[6]);
            gacc[7] = fmaf(xv[u], wb2.w, gacc[7]);
        }
#pragma unroll
        for (int off = 32; off > 0; off >>= 1)
#pragma unroll
            for (int e = 0; e < 8; ++e)
                gacc[e] += __shfl_xor(gacc[e], off, 64);
        if (lane == 0) {
            float l[8];
#pragma unroll
            for (int e = 0; e < 8; ++e) l[e] = gacc[e] + bg[e];
            int E0 = 0;
            for (int e = 1; e < 8; ++e) if (l[e] > l[E0]) E0 = e;
            int E1 = (E0 == 0) ? 1 : 0;
            for (int e = 0; e < 8; ++e) {
                if (e == E0) continue;
                if (l[e] > l[E1]) E1 = e;
            }
            float w0 = 1.f / (1.f + expf(l[E1] - l[E0]));  // p0/(p0+p1)
            tok_e[t * 2]     = E0;
            tok_e[t * 2 + 1] = E1;
            tok_w[t * 2]     = w0;
            tok_w[t * 2 + 1] = 1.f - w0;
        }
    }

    // ---- transpose one 64k x 256n tile ----
    const float* src; __bf16* dst; int NWs, KT, k0, n0;
    if (b < 512) {
        const int e = b >> 6, t = b & 63;
        src = W1f + (size_t)e * I_DIM * H_DIM;
        dst = W1T + (size_t)e * H_DIM * I_DIM;
        NWs = H_DIM; KT = I_DIM;
        k0 = (t >> 3) * 64; n0 = (t & 7) * 256;
    } else {
        const int u = b - 512, e = u >> 6, t = u & 63;
        src = W2f + (size_t)e * H_DIM * O_DIM;
        dst = W2T + (size_t)e * O_DIM * H_DIM;
        NWs = O_DIM; KT = H_DIM;
        k0 = (t >> 1) * 64; n0 = (t & 1) * 256;
    }
    __shared__ uint32_t T[256 * 33];     // [n][k-pair] packed bf16x2, 33 KB
#pragma unroll
    for (int i = 0; i < 8; ++i) {        // 2048 read units / 256 thr
        const int u = tid + 256 * i;
        const int p = u >> 6, c4 = u & 63;      // k-pair, n-quad
        const float* wp = src + (size_t)(k0 + 2 * p) * NWs + n0 + c4 * 4;
        float4 r0 = *(const float4*)wp;
        float4 r1 = *(const float4*)(wp + NWs);
        const float* f0 = (const float*)&r0;
        const float* f1 = (const float*)&r1;
#pragma unroll
        for (int j = 0; j < 4; ++j) {
            bf16x2 pk;
            pk[0] = (__bf16)f0[j];
            pk[1] = (__bf16)f1[j];
            *(bf16x2*)&T[(c4 * 4 + j) * 33 + p] = pk;
        }
    }
    __syncthreads();
#pragma unroll
    for (int i = 0; i < 8; ++i) {        // 2048 write units (16B) / 256 thr
        const int v = tid + 256 * i;
        const int n = v >> 3, s = v & 7;
        uint4 d;
        d.x = T[n * 33 + s * 4 + 0];
        d.y = T[n * 33 + s * 4 + 1];
        d.z = T[n * 33 + s * 4 + 2];
        d.w = T[n * 33 + s * 4 + 3];
        *(uint4*)(dst + (size_t)(n0 + n) * KT + k0 + s * 8) = d;
    }
}

// ---------------------------------------------------------------------------
// fc1: grid (64 nx, 2 my, 8 e) = 1024 blocks x 256 thr (4 waves, 4 blk/CU).
// Wave strip = 32m x 32n x 512k, depth-4 register prefetch (16 loads in
// flight). B streams W1T [n][k]; A gathers xb rows via ballot-scan slot list.
__global__ __launch_bounds__(256, 4) void fc1_kernel(
    const __bf16* __restrict__ xb, const __bf16* __restrict__ W1T,
    const float* __restrict__ b1, const int* __restrict__ tok_e,
    int* __restrict__ counts, int* __restrict__ tok_slot,
    __bf16* __restrict__ hb)
{
    const int tid = threadIdx.x, lane = tid & 63, w = tid >> 6;
    const int l15 = lane & 15, q = lane >> 4;
    const int e = blockIdx.z, my = blockIdx.y, nx = blockIdx.x;
    const int n0 = nx * 32;

    __shared__ int sl[CAP];
    __shared__ int sMe;

    // wave-0 ballot scan: deterministic token-order slot list for expert e.
    if (w == 0) {
        int cnt = 0;
#pragma unroll
        for (int bb = 0; bb < 2; ++bb) {
            int vals[16];
#pragma unroll
            for (int c = 0; c < 16; ++c)
                vals[c] = tok_e[(bb * 16 + c) * 64 + lane];
#pragma unroll
            for (int c = 0; c < 16; ++c) {
                const int gidx = (bb * 16 + c) * 64 + lane;
                const bool hit = (vals[c] == e);
                const unsigned long long mk = __ballot(hit);
                if (hit) {
                    const int pos = cnt + __popcll(mk & ((1ull << lane) - 1));
                    sl[pos] = gidx >> 1;
                    if (nx == 0 && my == 0) tok_slot[gidx] = e * CAP + pos;
                }
                cnt += __popcll(mk);
            }
        }
        if (lane == 0) {
            sMe = cnt;
            if (nx == 0 && my == 0) counts[e] = cnt;
        }
    }
    __syncthreads();
    const int Me = sMe;

    const __bf16* Wt  = W1T + (size_t)e * H_DIM * I_DIM;
    const __bf16* bp0 = Wt + (size_t)(n0 + l15) * I_DIM + q * 8;
    const __bf16* bp1 = bp0 + (size_t)16 * I_DIM;

    for (int m0 = my * 128 + w * 32; m0 < Me; m0 += 256) {
        int mA = m0 + l15;      if (mA >= Me) mA = Me - 1;
        int mB = m0 + 16 + l15; if (mB >= Me) mB = Me - 1;
        const __bf16* a0 = xb + (size_t)sl[mA] * I_DIM + q * 8;
        const __bf16* a1 = xb + (size_t)sl[mB] * I_DIM + q * 8;

        f32x4 acc[2][2] = {};
        bf16x8 pa0[4], pa1[4], pb0[4], pb1[4];
#pragma unroll
        for (int i = 0; i < 4; ++i) {           // prime pipeline: ks 0..3
            pa0[i] = *(const bf16x8*)(a0 + i * 32);
            pa1[i] = *(const bf16x8*)(a1 + i * 32);
            pb0[i] = *(const bf16x8*)(bp0 + i * 32);
            pb1[i] = *(const bf16x8*)(bp1 + i * 32);
        }
#pragma unroll
        for (int ks = 0; ks < 16; ++ks) {       // static slot: full unroll
            const int s = ks & 3;
            acc[0][0] = MFMA16(pa0[s], pb0[s], acc[0][0], 0, 0, 0);
            acc[1][0] = MFMA16(pa1[s], pb0[s], acc[1][0], 0, 0, 0);
            acc[0][1] = MFMA16(pa0[s], pb1[s], acc[0][1], 0, 0, 0);
            acc[1][1] = MFMA16(pa1[s], pb1[s], acc[1][1], 0, 0, 0);
            if (ks < 12) {                      // refill slot with ks+4
                pa0[s] = *(const bf16x8*)(a0 + (ks + 4) * 32);
                pa1[s] = *(const bf16x8*)(a1 + (ks + 4) * 32);
                pb0[s] = *(const bf16x8*)(bp0 + (ks + 4) * 32);
                pb1[s] = *(const bf16x8*)(bp1 + (ks + 4) * 32);
            }
        }
        // epilogue: C/D layout col=l15, row=q*4+r (verified m89)
#pragma unroll
        for (int jj = 0; jj < 2; ++jj) {
            const int gn = n0 + jj * 16 + l15;
            const float bv = b1[e * H_DIM + gn];
#pragma unroll
            for (int i = 0; i < 2; ++i)
#pragma unroll
                for (int r = 0; r < 4; ++r) {
                    int m = m0 + i * 16 + q * 4 + r;
                    if (m < Me) {
                        float v = acc[i][jj][r] + bv;
                        hb[(size_t)(e * CAP + m) * H_DIM + gn] =
                            (__bf16)fmaxf(v, 0.f);
                    }
                }
        }
    }
}

// ---------------------------------------------------------------------------
// fc2: grid (16 nx, 4 (my|kc<<1), 8 e) = 512 blocks x 256 thr (4 waves).
// Wave strip = 32m x 32n x 1024k (kc half), depth-4 register prefetch.
__global__ __launch_bounds__(256, 4) void fc2_kernel(
    const __bf16* __restrict__ hb, const __bf16* __restrict__ W2T,
    const int* __restrict__ counts, float* __restrict__ y2)
{
    const int tid = threadIdx.x, lane = tid & 63, w = tid >> 6;
    const int l15 = lane & 15, q = lane >> 4;
    const int e = blockIdx.z;
    const int my = blockIdx.y & 1, kc = blockIdx.y >> 1;
    const int n0 = blockIdx.x * 32;
    const int k0 = kc * 1024;

    const int Me = counts[e];
    if (Me == 0) return;

    const __bf16* Wt  = W2T + (size_t)e * O_DIM * H_DIM;
    const __bf16* bp0 = Wt + (size_t)(n0 + l15) * H_DIM + k0 + q * 8;
    const __bf16* bp1 = bp0 + (size_t)16 * H_DIM;

    for (int m0 = my * 128 + w * 32; m0 < Me; m0 += 256) {
        int mA = m0 + l15;      if (mA >= Me) mA = Me - 1;
        int mB = m0 + 16 + l15; if (mB >= Me) mB = Me - 1;
        const __bf16* a0 = hb + (size_t)(e * CAP + mA) * H_DIM + k0 + q * 8;
        const __bf16* a1 = hb + (size_t)(e * CAP + mB) * H_DIM + k0 + q * 8;

        f32x4 acc[2][2] = {};
        bf16x8 pa0[4], pa1[4], pb0[4], pb1[4];
#pragma unroll
        for (int i = 0; i < 4; ++i) {           // prime pipeline: ks 0..3
            pa0[i] = *(const bf16x8*)(a0 + i * 32);
            pa1[i] = *(const bf16x8*)(a1 + i * 32);
            pb0[i] = *(const bf16x8*)(bp0 + i * 32);
            pb1[i] = *(const bf16x8*)(bp1 + i * 32);
        }
#pragma unroll
        for (int ks = 0; ks < 32; ++ks) {       // static slot: full unroll
            const int s = ks & 3;
            acc[0][0] = MFMA16(pa0[s], pb0[s], acc[0][0], 0, 0, 0);
            acc[1][0] = MFMA16(pa1[s], pb0[s], acc[1][0], 0, 0, 0);
            acc[0][1] = MFMA16(pa0[s], pb1[s], acc[0][1], 0, 0, 0);
            acc[1][1] = MFMA16(pa1[s], pb1[s], acc[1][1], 0, 0, 0);
            if (ks < 28) {                      // refill slot with ks+4
                pa0[s] = *(const bf16x8*)(a0 + (ks + 4) * 32);
                pa1[s] = *(const bf16x8*)(a1 + (ks + 4) * 32);
                pb0[s] = *(const bf16x8*)(bp0 + (ks + 4) * 32);
                pb1[s] = *(const bf16x8*)(bp1 + (ks + 4) * 32);
            }
        }
#pragma unroll
        for (int jj = 0; jj < 2; ++jj) {
            const int gn = n0 + jj * 16 + l15;
#pragma unroll
            for (int i = 0; i < 2; ++i)
#pragma unroll
                for (int r = 0; r < 4; ++r) {
                    int m = m0 + i * 16 + q * 4 + r;
                    if (m < Me)
                        y2[((size_t)kc * (E_NUM * CAP) + e * CAP + m) * O_DIM + gn] =
                            acc[i][jj][r];
                }
        }
    }
}

// ---------------------------------------------------------------------------
// out[t][c] = sum_k w_k * (b2[e_k][c] + sum_kc y2[kc][slot_k][c])
__global__ __launch_bounds__(256) void combine_kernel(
    const float* __restrict__ y2, const float* __restrict__ b2,
    const int* __restrict__ tok_slot, const int* __restrict__ tok_e,
    const float* __restrict__ tok_w, float* __restrict__ out)
{
    const int idx = blockIdx.x * 256 + threadIdx.x;   // B*O/4
    const int t = idx >> 7;
    const int c = (idx & 127) * 4;
    float4 sum = {0.f, 0.f, 0.f, 0.f};
#pragma unroll
    for (int k = 0; k < 2; ++k) {
        const int s = tok_slot[t * 2 + k];
        const int e = tok_e[t * 2 + k];
        const float wgt = tok_w[t * 2 + k];
        float4 a = *(const float4*)(b2 + (size_t)e * O_DIM + c);
#pragma unroll
        for (int kc = 0; kc < 2; ++kc) {
            float4 v = *(const float4*)
                (y2 + ((size_t)kc * (E_NUM * CAP) + s) * O_DIM + c);
            a.x += v.x; a.y += v.y; a.z += v.z; a.w += v.w;
        }
        sum.x += wgt * a.x; sum.y += wgt * a.y;
        sum.z += wgt * a.z; sum.w += wgt * a.w;
    }
    *(float4*)(out + (size_t)t * O_DIM + c) = sum;
}

// ===========================================================================
extern "C" void kernel_launch(void* const* d_in, const int* in_sizes, int n_in,
                              void* d_out, int out_size, void* d_ws, size_t ws_size,
                              hipStream_t stream)
{
    const float* x  = (const float*)d_in[0];
    const float* Wg = (const float*)d_in[1];
    const float* bg = (const float*)d_in[2];
    const float* W1 = (const float*)d_in[3];
    const float* b1 = (const float*)d_in[4];
    const float* W2 = (const float*)d_in[5];
    const float* b2 = (const float*)d_in[6];
    float* out = (float*)d_out;
    char* ws = (char*)d_ws;

    int*    counts   = (int*)(ws + WS_COUNTS);
    int*    tok_e    = (int*)(ws + WS_TOK_E);
    float*  tok_w    = (float*)(ws + WS_TOK_W);
    int*    tok_slot = (int*)(ws + WS_TOK_SLOT);
    __bf16* xb       = (__bf16*)(ws + WS_XB);
    __bf16* W1T      = (__bf16*)(ws + WS_W1T);
    __bf16* W2T      = (__bf16*)(ws + WS_W2T);
    __bf16* hb       = (__bf16*)(ws + WS_HB);
    float*  y2       = (float*)(ws + WS_Y2);

    // gating + W-transpose/convert (1024 blocks: 96 MB streamed)
    prep_kernel<<<1024, 256, 0, stream>>>(x, Wg, bg, W1, W2,
                                          xb, tok_e, tok_w, W1T, W2T);
    // fc1: 64 n-panels x 2 m-halves x 8 experts = 1024 blocks (4/CU)
    fc1_kernel<<<dim3(64, 2, 8), 256, 0, stream>>>(
        xb, W1T, b1, tok_e, counts, tok_slot, hb);
    // fc2: 16 n-panels x (2 my x 2 kc) x 8 experts = 512 blocks (2/CU)
    fc2_kernel<<<dim3(16, 4, 8), 256, 0, stream>>>(hb, W2T, counts, y2);
    combine_kernel<<<(B_TOK * O_DIM / 4) / 256, 256, 0, stream>>>(
        y2, b2, tok_slot, tok_e, tok_w, out);
}

// Round 5
// 195.642 us; speedup vs baseline: 1.2058x; 1.2058x over previous
//
#include <hip/hip_runtime.h>
#include <math.h>

// MoE top-2-of-8: B=1024, I=512, H=2048, O=512, E=8, K=2.
// R13: LDS-staged weight-stationary GEMMs via global_load_lds (the R8-R12
// designs never used it; R11/R12 counters showed per-lane B-streaming is
// 16x wave-redundant -> fc2 moved 194 MB). Structure:
//  - prep: gating + W1/W2 -> bf16 [n][k] (W1T/W2T), unchanged R12.
//  - fc1/fc2: per block, stage one W-panel (64 KB) ONCE into LDS as 64
//    fragment-linear 1KB subtiles (16n x 32k in MFMA lane order) using
//    __builtin_amdgcn_global_load_lds width=16: LDS dest linear (wave base +
//    lane*16), per-lane global src supplies the fragment permutation ->
//    conflict-free ds_read_b128 at subtile*1024 + lane*16, no swizzle.
//    One __syncthreads per block; A streams per-lane k-contiguous (tiny).
//  - fc1: grid (32nx,2my,8e)=512 blk x 256 thr, BN=64, K=512, 2 blk/CU.
//  - fc2: grid (16nx,2my x 2kc,8e)=512 blk, BN=32, K-half=1024 -> y2 partials.
//  - combine: unchanged.
// NOTE: dur_us includes ~81us of harness 256MB poison fills (2 x 40.5us).

#define B_TOK 1024
#define I_DIM 512
#define H_DIM 2048
#define O_DIM 512
#define E_NUM 8
#define CAP   1024                       // per-expert slot capacity

#define WS_COUNTS   0                    // 8 ints (written by fc1 nx==0,my==0)
#define WS_TOK_E    64                   // [1024][2] int
#define WS_TOK_W    8256                 // [1024][2] float
#define WS_TOK_SLOT 16448                // [1024][2] int
#define WS_XB       65536                // [1024][512] bf16 = 1 MB
#define WS_W1T      1114112              // [8][2048][512] bf16 = 16 MB
#define WS_W2T      17891328             // [8][512][2048] bf16 = 16 MB
#define WS_HB       34668544             // [8*1024][2048] bf16 = 32 MB
#define WS_Y2       68222976             // [2][8192][512] f32 = 32 MB

typedef __attribute__((ext_vector_type(8))) __bf16 bf16x8;
typedef __attribute__((ext_vector_type(4))) __bf16 bf16x4;
typedef __attribute__((ext_vector_type(2))) __bf16 bf16x2;
typedef __attribute__((ext_vector_type(4))) float f32x4;

#define MFMA16 __builtin_amdgcn_mfma_f32_16x16x32_bf16

// async global->LDS, 16B per lane; LDS dest = wave-uniform base + lane*16,
// global src is per-lane (CK-style addrspace casts).
__device__ __forceinline__ void gll16(const __bf16* g, __bf16* l)
{
    __builtin_amdgcn_global_load_lds(
        (const __attribute__((address_space(1))) uint32_t*)g,
        (__attribute__((address_space(3))) uint32_t*)(uintptr_t)(void*)l,
        16, 0, 0);
}

// ---------------------------------------------------------------------------
// prep: blocks 0..255 gate 4 tokens each (one per wave) + convert x->xb bf16;
// ALL 1024 blocks then transpose one 64k x 256n W-tile to bf16 [n][k].
__global__ __launch_bounds__(256) void prep_kernel(
    const float* __restrict__ x, const float* __restrict__ Wg,
    const float* __restrict__ bg, const float* __restrict__ W1f,
    const float* __restrict__ W2f,
    __bf16* __restrict__ xb, int* __restrict__ tok_e,
    float* __restrict__ tok_w,
    __bf16* __restrict__ W1T, __bf16* __restrict__ W2T)
{
    const int tid = threadIdx.x, lane = tid & 63, w = tid >> 6;
    const int b = blockIdx.x;

    // ---- gating (blocks 0..255, one token per wave) ----
    if (b < 256) {
        const int t = b * 4 + w;
        const float4* x4 = (const float4*)(x + (size_t)t * I_DIM);
        float4 va = x4[lane], vb = x4[lane + 64];
        bf16x4 oa, ob;
        oa[0] = (__bf16)va.x; oa[1] = (__bf16)va.y;
        oa[2] = (__bf16)va.z; oa[3] = (__bf16)va.w;
        ob[0] = (__bf16)vb.x; ob[1] = (__bf16)vb.y;
        ob[2] = (__bf16)vb.z; ob[3] = (__bf16)vb.w;
        *(bf16x4*)(xb + (size_t)t * I_DIM + lane * 4) = oa;
        *(bf16x4*)(xb + (size_t)t * I_DIM + 256 + lane * 4) = ob;

        float gacc[8];
#pragma unroll
        for (int e = 0; e < 8; ++e) gacc[e] = 0.f;
        float xv[8] = {va.x, va.y, va.z, va.w, vb.x, vb.y, vb.z, vb.w};
#pragma unroll
        for (int u = 0; u < 8; ++u) {
            int i = (u < 4) ? (lane * 4 + u) : (256 + lane * 4 + u - 4);
            const float4* wr = (const float4*)(Wg + (size_t)i * 8);
            float4 wa = wr[0], wb2 = wr[1];
            gacc[0] = fmaf(xv[u], wa.x, gacc[0]);
            gacc[1] = fmaf(xv[u], wa.y, gacc[1]);
            gacc[2] = fmaf(xv[u], wa.z, gacc[2]);
            gacc[3] = fmaf(xv[u], wa.w, gacc[3]);
            gacc[4] = fmaf(xv[u], wb2.x, gacc[4]);
            gacc[5] = fmaf(xv[u], wb2.y, gacc[5]);
            gacc[6] = fmaf(xv[u], wb2.z, gacc[6]);
            gacc[7] = fmaf(xv[u], wb2.w, gacc[7]);
        }
#pragma unroll
        for (int off = 32; off > 0; off >>= 1)
#pragma unroll
            for (int e = 0; e < 8; ++e)
                gacc[e] += __shfl_xor(gacc[e], off, 64);
        if (lane == 0) {
            float l[8];
#pragma unroll
            for (int e = 0; e < 8; ++e) l[e] = gacc[e] + bg[e];
            int E0 = 0;
            for (int e = 1; e < 8; ++e) if (l[e] > l[E0]) E0 = e;
            int E1 = (E0 == 0) ? 1 : 0;
            for (int e = 0; e < 8; ++e) {
                if (e == E0) continue;
                if (l[e] > l[E1]) E1 = e;
            }
            float w0 = 1.f / (1.f + expf(l[E1] - l[E0]));  // p0/(p0+p1)
            tok_e[t * 2]     = E0;
            tok_e[t * 2 + 1] = E1;
            tok_w[t * 2]     = w0;
            tok_w[t * 2 + 1] = 1.f - w0;
        }
    }

    // ---- transpose one 64k x 256n tile ----
    const float* src; __bf16* dst; int NWs, KT, k0, n0;
    if (b < 512) {
        const int e = b >> 6, t = b & 63;
        src = W1f + (size_t)e * I_DIM * H_DIM;
        dst = W1T + (size_t)e * H_DIM * I_DIM;
        NWs = H_DIM; KT = I_DIM;
        k0 = (t >> 3) * 64; n0 = (t & 7) * 256;
    } else {
        const int u = b - 512, e = u >> 6, t = u & 63;
        src = W2f + (size_t)e * H_DIM * O_DIM;
        dst = W2T + (size_t)e * O_DIM * H_DIM;
        NWs = O_DIM; KT = H_DIM;
        k0 = (t >> 1) * 64; n0 = (t & 1) * 256;
    }
    __shared__ uint32_t T[256 * 33];     // [n][k-pair] packed bf16x2, 33 KB
#pragma unroll
    for (int i = 0; i < 8; ++i) {        // 2048 read units / 256 thr
        const int u = tid + 256 * i;
        const int p = u >> 6, c4 = u & 63;      // k-pair, n-quad
        const float* wp = src + (size_t)(k0 + 2 * p) * NWs + n0 + c4 * 4;
        float4 r0 = *(const float4*)wp;
        float4 r1 = *(const float4*)(wp + NWs);
        const float* f0 = (const float*)&r0;
        const float* f1 = (const float*)&r1;
#pragma unroll
        for (int j = 0; j < 4; ++j) {
            bf16x2 pk;
            pk[0] = (__bf16)f0[j];
            pk[1] = (__bf16)f1[j];
            *(bf16x2*)&T[(c4 * 4 + j) * 33 + p] = pk;
        }
    }
    __syncthreads();
#pragma unroll
    for (int i = 0; i < 8; ++i) {        // 2048 write units (16B) / 256 thr
        const int v = tid + 256 * i;
        const int n = v >> 3, s = v & 7;
        uint4 d;
        d.x = T[n * 33 + s * 4 + 0];
        d.y = T[n * 33 + s * 4 + 1];
        d.z = T[n * 33 + s * 4 + 2];
        d.w = T[n * 33 + s * 4 + 3];
        *(uint4*)(dst + (size_t)(n0 + n) * KT + k0 + s * 8) = d;
    }
}

// ---------------------------------------------------------------------------
// fc1: grid (32 nx, 2 my, 8 e) = 512 blocks x 256 thr (4 waves, 2 blk/CU).
// Stage 64n x 512k W1T panel once into 64 fragment-linear LDS subtiles via
// global_load_lds; then each wave computes 32m x 64n with A per-lane direct.
__global__ __launch_bounds__(256, 2) void fc1_kernel(
    const __bf16* __restrict__ xb, const __bf16* __restrict__ W1T,
    const float* __restrict__ b1, const int* __restrict__ tok_e,
    int* __restrict__ counts, int* __restrict__ tok_slot,
    __bf16* __restrict__ hb)
{
    const int tid = threadIdx.x, lane = tid & 63, w = tid >> 6;
    const int l15 = lane & 15, q = lane >> 4;
    const int e = blockIdx.z, my = blockIdx.y, nx = blockIdx.x;
    const int n0 = nx * 64;

    __shared__ __align__(16) __bf16 Bs[64 * 512];   // 64 x 1KB subtiles, 64 KB
    __shared__ int sl[CAP];
    __shared__ int sMe;

    const __bf16* Wt = W1T + (size_t)e * H_DIM * I_DIM;

    // ---- issue async staging: subtile s = jj*16+ks holds rows n0+jj*16..+15,
    // k ks*32..+31 in MFMA lane order (lane l -> row l&15, k-chunk l>>4).
#pragma unroll
    for (int i = 0; i < 16; ++i) {
        const int s = w * 16 + i;
        const int jj = s >> 4, ks = s & 15;
        const __bf16* g = Wt + (size_t)(n0 + jj * 16 + l15) * I_DIM
                          + ks * 32 + q * 8;
        gll16(g, Bs + s * 512);
    }

    // ---- wave-0 ballot scan (overlaps staging): token-order slot list.
    if (w == 0) {
        int cnt = 0;
#pragma unroll
        for (int bb = 0; bb < 2; ++bb) {
            int vals[16];
#pragma unroll
            for (int c = 0; c < 16; ++c)
                vals[c] = tok_e[(bb * 16 + c) * 64 + lane];
#pragma unroll
            for (int c = 0; c < 16; ++c) {
                const int gidx = (bb * 16 + c) * 64 + lane;
                const bool hit = (vals[c] == e);
                const unsigned long long mk = __ballot(hit);
                if (hit) {
                    const int pos = cnt + __popcll(mk & ((1ull << lane) - 1));
                    sl[pos] = gidx >> 1;
                    if (nx == 0 && my == 0) tok_slot[gidx] = e * CAP + pos;
                }
                cnt += __popcll(mk);
            }
        }
        if (lane == 0) {
            sMe = cnt;
            if (nx == 0 && my == 0) counts[e] = cnt;
        }
    }
    __syncthreads();                     // staging (vmcnt drain) + scan ready
    const int Me = sMe;

    for (int m0 = my * 128 + w * 32; m0 < Me; m0 += 256) {
        int mA = m0 + l15;      if (mA >= Me) mA = Me - 1;
        int mB = m0 + 16 + l15; if (mB >= Me) mB = Me - 1;
        const __bf16* a0 = xb + (size_t)sl[mA] * I_DIM + q * 8;
        const __bf16* a1 = xb + (size_t)sl[mB] * I_DIM + q * 8;

        f32x4 acc[2][4] = {};
#pragma unroll
        for (int ks = 0; ks < 16; ++ks) {
            bf16x8 af0 = *(const bf16x8*)(a0 + ks * 32);
            bf16x8 af1 = *(const bf16x8*)(a1 + ks * 32);
#pragma unroll
            for (int jj = 0; jj < 4; ++jj) {
                bf16x8 bf = *(const bf16x8*)&Bs[(jj * 16 + ks) * 512 + lane * 8];
                acc[0][jj] = MFMA16(af0, bf, acc[0][jj], 0, 0, 0);
                acc[1][jj] = MFMA16(af1, bf, acc[1][jj], 0, 0, 0);
            }
        }
        // epilogue: C/D layout col=l15, row=q*4+r (verified m89)
#pragma unroll
        for (int jj = 0; jj < 4; ++jj) {
            const int gn = n0 + jj * 16 + l15;
            const float bv = b1[e * H_DIM + gn];
#pragma unroll
            for (int i = 0; i < 2; ++i)
#pragma unroll
                for (int r = 0; r < 4; ++r) {
                    int m = m0 + i * 16 + q * 4 + r;
                    if (m < Me) {
                        float v = acc[i][jj][r] + bv;
                        hb[(size_t)(e * CAP + m) * H_DIM + gn] =
                            (__bf16)fmaxf(v, 0.f);
                    }
                }
        }
    }
}

// ---------------------------------------------------------------------------
// fc2: grid (16 nx, 4 (my|kc<<1), 8 e) = 512 blocks x 256 thr (2 blk/CU).
// Stage 32n x 1024k W2T half-panel once (64 subtiles); y2 f32 partials.
__global__ __launch_bounds__(256, 2) void fc2_kernel(
    const __bf16* __restrict__ hb, const __bf16* __restrict__ W2T,
    const int* __restrict__ counts, float* __restrict__ y2)
{
    const int tid = threadIdx.x, lane = tid & 63, w = tid >> 6;
    const int l15 = lane & 15, q = lane >> 4;
    const int e = blockIdx.z;
    const int my = blockIdx.y & 1, kc = blockIdx.y >> 1;
    const int n0 = blockIdx.x * 32;
    const int k0 = kc * 1024;

    const int Me = counts[e];
    if (Me == 0) return;

    __shared__ __align__(16) __bf16 Bs[64 * 512];   // 64 KB

    const __bf16* Wt = W2T + (size_t)e * O_DIM * H_DIM;

    // subtile s = jj*32+ks: rows n0+jj*16..+15, k k0+ks*32..+31, lane order.
#pragma unroll
    for (int i = 0; i < 16; ++i) {
        const int s = w * 16 + i;
        const int jj = s >> 5, ks = s & 31;
        const __bf16* g = Wt + (size_t)(n0 + jj * 16 + l15) * H_DIM
                          + k0 + ks * 32 + q * 8;
        gll16(g, Bs + s * 512);
    }
    __syncthreads();                     // staging resident

    for (int m0 = my * 128 + w * 32; m0 < Me; m0 += 256) {
        int mA = m0 + l15;      if (mA >= Me) mA = Me - 1;
        int mB = m0 + 16 + l15; if (mB >= Me) mB = Me - 1;
        const __bf16* a0 = hb + (size_t)(e * CAP + mA) * H_DIM + k0 + q * 8;
        const __bf16* a1 = hb + (size_t)(e * CAP + mB) * H_DIM + k0 + q * 8;

        f32x4 acc[2][2] = {};
#pragma unroll
        for (int ks = 0; ks < 32; ++ks) {
            bf16x8 af0 = *(const bf16x8*)(a0 + ks * 32);
            bf16x8 af1 = *(const bf16x8*)(a1 + ks * 32);
#pragma unroll
            for (int jj = 0; jj < 2; ++jj) {
                bf16x8 bf = *(const bf16x8*)&Bs[(jj * 32 + ks) * 512 + lane * 8];
                acc[0][jj] = MFMA16(af0, bf, acc[0][jj], 0, 0, 0);
                acc[1][jj] = MFMA16(af1, bf, acc[1][jj], 0, 0, 0);
            }
        }
#pragma unroll
        for (int jj = 0; jj < 2; ++jj) {
            const int gn = n0 + jj * 16 + l15;
#pragma unroll
            for (int i = 0; i < 2; ++i)
#pragma unroll
                for (int r = 0; r < 4; ++r) {
                    int m = m0 + i * 16 + q * 4 + r;
                    if (m < Me)
                        y2[((size_t)kc * (E_NUM * CAP) + e * CAP + m) * O_DIM + gn] =
                            acc[i][jj][r];
                }
        }
    }
}

// ---------------------------------------------------------------------------
// out[t][c] = sum_k w_k * (b2[e_k][c] + sum_kc y2[kc][slot_k][c])
__global__ __launch_bounds__(256) void combine_kernel(
    const float* __restrict__ y2, const float* __restrict__ b2,
    const int* __restrict__ tok_slot, const int* __restrict__ tok_e,
    const float* __restrict__ tok_w, float* __restrict__ out)
{
    const int idx = blockIdx.x * 256 + threadIdx.x;   // B*O/4
    const int t = idx >> 7;
    const int c = (idx & 127) * 4;
    float4 sum = {0.f, 0.f, 0.f, 0.f};
#pragma unroll
    for (int k = 0; k < 2; ++k) {
        const int s = tok_slot[t * 2 + k];
        const int e = tok_e[t * 2 + k];
        const float wgt = tok_w[t * 2 + k];
        float4 a = *(const float4*)(b2 + (size_t)e * O_DIM + c);
#pragma unroll
        for (int kc = 0; kc < 2; ++kc) {
            float4 v = *(const float4*)
                (y2 + ((size_t)kc * (E_NUM * CAP) + s) * O_DIM + c);
            a.x += v.x; a.y += v.y; a.z += v.z; a.w += v.w;
        }
        sum.x += wgt * a.x; sum.y += wgt * a.y;
        sum.z += wgt * a.z; sum.w += wgt * a.w;
    }
    *(float4*)(out + (size_t)t * O_DIM + c) = sum;
}

// ===========================================================================
extern "C" void kernel_launch(void* const* d_in, const int* in_sizes, int n_in,
                              void* d_out, int out_size, void* d_ws, size_t ws_size,
                              hipStream_t stream)
{
    const float* x  = (const float*)d_in[0];
    const float* Wg = (const float*)d_in[1];
    const float* bg = (const float*)d_in[2];
    const float* W1 = (const float*)d_in[3];
    const float* b1 = (const float*)d_in[4];
    const float* W2 = (const float*)d_in[5];
    const float* b2 = (const float*)d_in[6];
    float* out = (float*)d_out;
    char* ws = (char*)d_ws;

    int*    counts   = (int*)(ws + WS_COUNTS);
    int*    tok_e    = (int*)(ws + WS_TOK_E);
    float*  tok_w    = (float*)(ws + WS_TOK_W);
    int*    tok_slot = (int*)(ws + WS_TOK_SLOT);
    __bf16* xb       = (__bf16*)(ws + WS_XB);
    __bf16* W1T      = (__bf16*)(ws + WS_W1T);
    __bf16* W2T      = (__bf16*)(ws + WS_W2T);
    __bf16* hb       = (__bf16*)(ws + WS_HB);
    float*  y2       = (float*)(ws + WS_Y2);

    // gating + W-transpose/convert (1024 blocks: ~130 MB streamed)
    prep_kernel<<<1024, 256, 0, stream>>>(x, Wg, bg, W1, W2,
                                          xb, tok_e, tok_w, W1T, W2T);
    // fc1: 32 n-panels x 2 m-halves x 8 experts = 512 blocks (2/CU)
    fc1_kernel<<<dim3(32, 2, 8), 256, 0, stream>>>(
        xb, W1T, b1, tok_e, counts, tok_slot, hb);
    // fc2: 16 n-panels x (2 my x 2 kc) x 8 experts = 512 blocks (2/CU)
    fc2_kernel<<<dim3(16, 4, 8), 256, 0, stream>>>(hb, W2T, counts, y2);
    combine_kernel<<<(B_TOK * O_DIM / 4) / 256, 256, 0, stream>>>(
        y2, b2, tok_slot, tok_e, tok_w, out);
}

// Round 6
// 154.888 us; speedup vs baseline: 1.5231x; 1.2631x over previous
//
#include <hip/hip_runtime.h>
#include <math.h>

// MoE top-2-of-8: B=1024, I=512, H=2048, O=512, E=8, K=2.
// R14: return to the R8 GEMM core (best measured: ~73us of kernels) and fix
// its structural costs. No prep pass: W fp32 is staged straight into LDS with
// contiguous 128B row reads + fp32->bf16 k-pair-packed transpose writes
// ([n][k], BSTR=520, conflict-free reads -- R7/R8 proven). Changes vs R8:
//  - BN=32, single-shot 33KB panel stage, ONE barrier per block.
//  - 512 blocks x 512 thr, __launch_bounds__(512,4) -> 2 blocks/CU,
//    16 waves/CU (R8 ran 1 block/CU).
//  - nx fully partitions N: every W element fetched exactly once (R13's my=2
//    duplicated all W panels).
//  - expert->XCD affinity: e = blockIdx.x & 7, so an expert's blocks share
//    one XCD's L2 for xb / hb[e] re-reads.
//  - scatter fused into fc1 as the R9 wave-0 ballot scan (deterministic).
//  - fc2 kc=4 x 512k chunks -> y4 f32 partials (R8's summation order).
// NOTE: dur_us includes ~81us of harness 256MB poison fills (2 x 40.5us).

#define B_TOK 1024
#define I_DIM 512
#define H_DIM 2048
#define O_DIM 512
#define E_NUM 8
#define CAP   1024                       // per-expert slot capacity

#define WS_COUNTS   0                    // 8 ints (written by fc1 nx==0)
#define WS_TOK_E    64                   // [1024][2] int
#define WS_TOK_W    8256                 // [1024][2] float
#define WS_TOK_SLOT 16448                // [1024][2] int
#define WS_XB       65536                // [1024][512] bf16 = 1 MB
#define WS_HB       1114112              // [8*1024][2048] bf16 = 32 MB
#define WS_Y4       34668544             // [4][8192][512] f32 = 64 MB

typedef __attribute__((ext_vector_type(8))) __bf16 bf16x8;
typedef __attribute__((ext_vector_type(4))) __bf16 bf16x4;
typedef __attribute__((ext_vector_type(2))) __bf16 bf16x2;
typedef __attribute__((ext_vector_type(4))) float f32x4;

#define MFMA16 __builtin_amdgcn_mfma_f32_16x16x32_bf16
#define BSTR 520   // LDS row stride (512 + 8 pad): conflict-free frag reads

// ---------------------------------------------------------------------------
// Gating: one wave per token. Also converts the token's x row to bf16 (xb).
__global__ __launch_bounds__(256) void gating_kernel(
    const float* __restrict__ x, const float* __restrict__ Wg,
    const float* __restrict__ bg, __bf16* __restrict__ xb,
    int* __restrict__ tok_e, float* __restrict__ tok_w)
{
    const int lane = threadIdx.x & 63;
    const int t = blockIdx.x * 4 + (threadIdx.x >> 6);
    const float4* x4 = (const float4*)(x + (size_t)t * I_DIM);
    float4 va = x4[lane], vb = x4[lane + 64];
    bf16x4 oa, ob;
    oa[0] = (__bf16)va.x; oa[1] = (__bf16)va.y;
    oa[2] = (__bf16)va.z; oa[3] = (__bf16)va.w;
    ob[0] = (__bf16)vb.x; ob[1] = (__bf16)vb.y;
    ob[2] = (__bf16)vb.z; ob[3] = (__bf16)vb.w;
    *(bf16x4*)(xb + (size_t)t * I_DIM + lane * 4) = oa;
    *(bf16x4*)(xb + (size_t)t * I_DIM + 256 + lane * 4) = ob;

    float acc[8];
#pragma unroll
    for (int e = 0; e < 8; ++e) acc[e] = 0.f;
    float xv[8] = {va.x, va.y, va.z, va.w, vb.x, vb.y, vb.z, vb.w};
#pragma unroll
    for (int u = 0; u < 8; ++u) {
        int i = (u < 4) ? (lane * 4 + u) : (256 + lane * 4 + u - 4);
        const float4* wr = (const float4*)(Wg + (size_t)i * 8);
        float4 wa = wr[0], wb2 = wr[1];
        acc[0] = fmaf(xv[u], wa.x, acc[0]);
        acc[1] = fmaf(xv[u], wa.y, acc[1]);
        acc[2] = fmaf(xv[u], wa.z, acc[2]);
        acc[3] = fmaf(xv[u], wa.w, acc[3]);
        acc[4] = fmaf(xv[u], wb2.x, acc[4]);
        acc[5] = fmaf(xv[u], wb2.y, acc[5]);
        acc[6] = fmaf(xv[u], wb2.z, acc[6]);
        acc[7] = fmaf(xv[u], wb2.w, acc[7]);
    }
#pragma unroll
    for (int off = 32; off > 0; off >>= 1)
#pragma unroll
        for (int e = 0; e < 8; ++e)
            acc[e] += __shfl_xor(acc[e], off, 64);
    if (lane == 0) {
        float l[8];
#pragma unroll
        for (int e = 0; e < 8; ++e) l[e] = acc[e] + bg[e];
        int e0 = 0;
        for (int e = 1; e < 8; ++e) if (l[e] > l[e0]) e0 = e;
        int e1 = (e0 == 0) ? 1 : 0;
        for (int e = 0; e < 8; ++e) {
            if (e == e0) continue;
            if (l[e] > l[e1]) e1 = e;
        }
        float w0 = 1.f / (1.f + expf(l[e1] - l[e0]));  // p0/(p0+p1)
        tok_e[t * 2]     = e0;
        tok_e[t * 2 + 1] = e1;
        tok_w[t * 2]     = w0;
        tok_w[t * 2 + 1] = 1.f - w0;
    }
}

// ---------------------------------------------------------------------------
// Weight-stationary GEMM, direct-fp32 contiguous staging (R8 core).
// 512 thr = 8 waves; BN=32 (JN=2); K-span 512 staged once (33KB), 1 barrier.
// Grid 512 blocks, e = bid&7 (XCD affinity), 2 blocks/CU.
// IS_FC1:  nx=bid>>3 (64), A=xb via ballot-scan slot list, Out=hb(+bias,relu)
// !IS_FC1: r=bid>>3: nx=r&15, kc=r>>4 (4 chunks); A=hb rows; Out=y4 partials
template <bool IS_FC1>
__global__ __launch_bounds__(512, 4) void moe_gemm(
    const __bf16* __restrict__ A, const float* __restrict__ Wf,
    const float* __restrict__ bias,
    int* __restrict__ counts, const int* __restrict__ tok_e,
    int* __restrict__ tok_slot,
    __bf16* __restrict__ hb, float* __restrict__ y4)
{
    constexpr int NW   = IS_FC1 ? H_DIM : O_DIM;   // W col count (row stride)
    constexpr int ASTR = IS_FC1 ? I_DIM : H_DIM;   // A row stride

    const int bid = blockIdx.x;
    const int e = bid & 7;
    const int r = bid >> 3;
    const int nx = IS_FC1 ? r : (r & 15);
    const int kc = IS_FC1 ? 0 : (r >> 4);
    const int n0 = nx * 32;
    const int kb = kc * 512;
    const int off = e * CAP;
    const float* W = Wf + (size_t)e * (IS_FC1 ? I_DIM * H_DIM : H_DIM * O_DIM);

    __shared__ __align__(16) __bf16 Bs[32 * BSTR];  // 33,280 B
    __shared__ int sl[IS_FC1 ? CAP : 1];
    __shared__ int sMe;

    const int tid = threadIdx.x;
    const int lane = tid & 63, w = tid >> 6;
    const int l15 = lane & 15, q = lane >> 4;

    // ---- stage 32n x 512k W-panel: contiguous 2x float4 per unit, k-pair
    // packed bf16x2 transpose writes into [n][k] (BSTR=520).
#pragma unroll
    for (int i = 0; i < 4; ++i) {
        const int u = tid + 512 * i;            // 2048 units
        const int p = u >> 3, c4 = u & 7;       // k-pair 0..255, n-quad 0..7
        const float* wp = W + (size_t)(kb + 2 * p) * NW + n0 + c4 * 4;
        float4 r0 = *(const float4*)wp;
        float4 r1 = *(const float4*)(wp + NW);
        const float* f0 = (const float*)&r0;
        const float* f1 = (const float*)&r1;
#pragma unroll
        for (int j = 0; j < 4; ++j) {
            bf16x2 pk;
            pk[0] = (__bf16)f0[j];
            pk[1] = (__bf16)f1[j];
            *(bf16x2*)&Bs[(size_t)(c4 * 4 + j) * BSTR + 2 * p] = pk;
        }
    }

    // ---- fc1: wave-0 ballot scan -> deterministic token-order slot list.
    if (IS_FC1 && w == 0) {
        int cnt = 0;
#pragma unroll
        for (int bb = 0; bb < 2; ++bb) {
            int vals[16];
#pragma unroll
            for (int c = 0; c < 16; ++c)
                vals[c] = tok_e[(bb * 16 + c) * 64 + lane];
#pragma unroll
            for (int c = 0; c < 16; ++c) {
                const int gidx = (bb * 16 + c) * 64 + lane;
                const bool hit = (vals[c] == e);
                const unsigned long long mk = __ballot(hit);
                if (hit) {
                    const int pos = cnt + __popcll(mk & ((1ull << lane) - 1));
                    sl[pos] = gidx >> 1;
                    if (nx == 0) tok_slot[gidx] = off + pos;
                }
                cnt += __popcll(mk);
            }
        }
        if (lane == 0) {
            sMe = cnt;
            if (nx == 0) counts[e] = cnt;
        }
    }
    __syncthreads();                     // panel + slot list resident
    const int Me = IS_FC1 ? sMe : counts[e];

    // ---- compute: each wave owns a 32m x 32n strip (8 waves cover 256 m).
    for (int m0 = w * 32; m0 < Me; m0 += 256) {
        int mA = m0 + l15;      if (mA >= Me) mA = Me - 1;
        int mB = m0 + 16 + l15; if (mB >= Me) mB = Me - 1;
        const __bf16 *a0, *a1;
        if (IS_FC1) {
            a0 = A + (size_t)sl[mA] * ASTR + q * 8;
            a1 = A + (size_t)sl[mB] * ASTR + q * 8;
        } else {
            a0 = A + (size_t)(off + mA) * ASTR + kb + q * 8;
            a1 = A + (size_t)(off + mB) * ASTR + kb + q * 8;
        }

        f32x4 acc[2][2] = {};
#pragma unroll 4
        for (int ks = 0; ks < 16; ++ks) {
            bf16x8 af0 = *(const bf16x8*)(a0 + ks * 32);
            bf16x8 af1 = *(const bf16x8*)(a1 + ks * 32);
#pragma unroll
            for (int jj = 0; jj < 2; ++jj) {
                bf16x8 bf = *(const bf16x8*)
                    &Bs[(size_t)(jj * 16 + l15) * BSTR + ks * 32 + q * 8];
                acc[0][jj] = MFMA16(af0, bf, acc[0][jj], 0, 0, 0);
                acc[1][jj] = MFMA16(af1, bf, acc[1][jj], 0, 0, 0);
            }
        }
        // epilogue: C/D layout col=l15, row=q*4+r (verified m89)
#pragma unroll
        for (int jj = 0; jj < 2; ++jj) {
            const int gn = n0 + jj * 16 + l15;
            if (IS_FC1) {
                const float bv = bias[e * H_DIM + gn];
#pragma unroll
                for (int i = 0; i < 2; ++i)
#pragma unroll
                    for (int rr = 0; rr < 4; ++rr) {
                        int m = m0 + i * 16 + q * 4 + rr;
                        if (m < Me) {
                            float v = acc[i][jj][rr] + bv;
                            hb[(size_t)(off + m) * H_DIM + gn] =
                                (__bf16)fmaxf(v, 0.f);
                        }
                    }
            } else {
#pragma unroll
                for (int i = 0; i < 2; ++i)
#pragma unroll
                    for (int rr = 0; rr < 4; ++rr) {
                        int m = m0 + i * 16 + q * 4 + rr;
                        if (m < Me)
                            y4[((size_t)kc * (E_NUM * CAP) + off + m) * O_DIM + gn] =
                                acc[i][jj][rr];
                    }
            }
        }
    }
}

// ---------------------------------------------------------------------------
// out[t][c] = sum_k w_k * (b2[e_k][c] + sum_kc y4[kc][slot_k][c])
__global__ __launch_bounds__(256) void combine_kernel(
    const float* __restrict__ y4, const float* __restrict__ b2,
    const int* __restrict__ tok_slot, const int* __restrict__ tok_e,
    const float* __restrict__ tok_w, float* __restrict__ out)
{
    const int idx = blockIdx.x * 256 + threadIdx.x;   // B*O/4
    const int t = idx >> 7;
    const int c = (idx & 127) * 4;
    float4 sum = {0.f, 0.f, 0.f, 0.f};
#pragma unroll
    for (int k = 0; k < 2; ++k) {
        const int s = tok_slot[t * 2 + k];
        const int e = tok_e[t * 2 + k];
        const float wgt = tok_w[t * 2 + k];
        float4 a = *(const float4*)(b2 + (size_t)e * O_DIM + c);
#pragma unroll
        for (int kc = 0; kc < 4; ++kc) {
            float4 v = *(const float4*)
                (y4 + ((size_t)kc * (E_NUM * CAP) + s) * O_DIM + c);
            a.x += v.x; a.y += v.y; a.z += v.z; a.w += v.w;
        }
        sum.x += wgt * a.x; sum.y += wgt * a.y;
        sum.z += wgt * a.z; sum.w += wgt * a.w;
    }
    *(float4*)(out + (size_t)t * O_DIM + c) = sum;
}

// ===========================================================================
extern "C" void kernel_launch(void* const* d_in, const int* in_sizes, int n_in,
                              void* d_out, int out_size, void* d_ws, size_t ws_size,
                              hipStream_t stream)
{
    const float* x  = (const float*)d_in[0];
    const float* Wg = (const float*)d_in[1];
    const float* bg = (const float*)d_in[2];
    const float* W1 = (const float*)d_in[3];
    const float* b1 = (const float*)d_in[4];
    const float* W2 = (const float*)d_in[5];
    const float* b2 = (const float*)d_in[6];
    float* out = (float*)d_out;
    char* ws = (char*)d_ws;

    int*    counts   = (int*)(ws + WS_COUNTS);
    int*    tok_e    = (int*)(ws + WS_TOK_E);
    float*  tok_w    = (float*)(ws + WS_TOK_W);
    int*    tok_slot = (int*)(ws + WS_TOK_SLOT);
    __bf16* xb       = (__bf16*)(ws + WS_XB);
    __bf16* hb       = (__bf16*)(ws + WS_HB);
    float*  y4       = (float*)(ws + WS_Y4);

    gating_kernel<<<B_TOK / 4, 256, 0, stream>>>(x, Wg, bg, xb, tok_e, tok_w);
    // fc1: 64 n-panels x 8 experts = 512 blocks (2/CU), e = bid&7
    moe_gemm<true><<<512, 512, 0, stream>>>(
        xb, W1, b1, counts, tok_e, tok_slot, hb, y4);
    // fc2: 16 n-panels x 4 k-chunks x 8 experts = 512 blocks (2/CU)
    moe_gemm<false><<<512, 512, 0, stream>>>(
        hb, W2, b2, counts, tok_e, tok_slot, hb, y4);
    combine_kernel<<<(B_TOK * O_DIM / 4) / 256, 256, 0, stream>>>(
        y4, b2, tok_slot, tok_e, tok_w, out);
}